// Round 12
// baseline (15848.512 us; speedup 1.0000x reference)
//
#include <hip/hip_runtime.h>
#include <hip/hip_fp16.h>

typedef __attribute__((ext_vector_type(4))) float f32x4;
typedef _Float16 f16;
typedef __attribute__((ext_vector_type(4))) _Float16 f16x4;
typedef __attribute__((ext_vector_type(8))) _Float16 f16x8;

#define DEV static __device__ __forceinline__

constexpr int B_ = 128, T_ = 2048, H_ = 256, TRG_ = 24;
constexpr int NBLK = 8;   // encoder blocks, 16 batches each

// ---------------- workspace layout (~150 MiB) ----------------
constexpr size_t XF_OFF   = 0;                                   // x A-fragments [t][blk][bb][32] f16
constexpr size_t XF_BYTES = (size_t)T_ * NBLK * 16 * 32 * 2;     // 16 MiB
constexpr size_t OUTS_OFF = XF_OFF + XF_BYTES;
constexpr size_t OUTS_BYTES = (size_t)B_ * T_ * H_ * 2;          // 128 MiB f16
constexpr size_t EPROJ_OFF = OUTS_OFF + OUTS_BYTES;
constexpr size_t EPROJ_BYTES = (size_t)B_ * T_ * 4;              // 1 MiB
constexpr size_t HH_OFF = EPROJ_OFF + EPROJ_BYTES;               // ping-pong decoder h (buf0 = enc final)
constexpr size_t HH_BYTES = 2ull * B_ * H_ * 4;
constexpr size_t CC_OFF = HH_OFF + HH_BYTES;
constexpr size_t CC_BYTES = (size_t)B_ * H_ * 4;
constexpr size_t WXD_OFF = CC_OFF + CC_BYTES;                    // Wih_d[:,1:] @ Wfc (1024x256) f32
constexpr size_t WXD_BYTES = 1024ull * 256 * 4;
constexpr size_t VV_OFF = WXD_OFF + WXD_BYTES;
constexpr size_t VV_BYTES = 8192;
constexpr size_t WALL_OFF = VV_OFF + VV_BYTES;                   // enc weights ks0-3 image (f16 frags)
constexpr size_t WALL_BYTES = 16384ull * 16;                     // 256 KiB
constexpr size_t W67_OFF = WALL_OFF + WALL_BYTES;                // streamed enc weights ks6,7 (x2 copies)
constexpr size_t W67_BYTES = 2ull * 8192 * 16;                   // 256 KiB
constexpr size_t XB_OFF = W67_OFF + W67_BYTES;                   // streamed x weights (x2 copies)
constexpr size_t XB_BYTES = 2ull * 4096 * 16;                    // 128 KiB
constexpr size_t ZERO_OFF = XB_OFF + XB_BYTES;
constexpr size_t CTX_CNT = 24ull * 128 * 257;   // ctxacc
constexpr size_t SAC_CNT = 25ull * 128;         // s_acc
constexpr size_t PRD_CNT = 24ull * 128;         // pred_acc
constexpr size_t INP_CNT = 25ull * 128;         // inp_buf
constexpr size_t ZERO_CNT = CTX_CNT + SAC_CNT + PRD_CNT + INP_CNT;
constexpr size_t WS_NEED = ZERO_OFF + ZERO_CNT * 4 + 1024;

// ---------------- helpers ----------------
DEV float sigf(float x)  { return 1.0f / (1.0f + __expf(-x)); }
DEV float tanh_(float x) { return 1.0f - 2.0f / (__expf(2.0f * x) + 1.0f); }

__global__ void k_wsfail(float* __restrict__ dout, float mb) { dout[0] = 1e6f + mb; }

__global__ void k_zero(float* __restrict__ p, size_t n) {
  size_t i = (size_t)blockIdx.x * blockDim.x + threadIdx.x;
  size_t s = (size_t)gridDim.x * blockDim.x;
  for (; i < n; i += s) p[i] = 0.f;
}

// ---------------- merged setup: vv (blk<8), wxd (blk<72), weight images (else) ----------------
__global__ void k_setup(const float* __restrict__ Wfc, const float* __restrict__ Wa,
                        const float* __restrict__ Wf2, const float* __restrict__ bf2_,
                        const float* __restrict__ bfc, const float* __restrict__ bihd,
                        const float* __restrict__ bhhd, const float* __restrict__ Wihd,
                        const float* __restrict__ Whh, const float* __restrict__ Wih,
                        const float* __restrict__ bih, const float* __restrict__ bhh,
                        float* __restrict__ vv, float* __restrict__ wxd,
                        f16* __restrict__ wall, f16* __restrict__ w67, f16* __restrict__ xb) {
  const int bid = blockIdx.x, tid = threadIdx.x;
  if (bid < 8) {
    const int blk = bid;
    if (blk == 0) {
      float a = 0; for (int h = 0; h < 256; ++h) a += Wfc[h * 256 + tid] * Wa[256 + h];
      vv[tid] = a;
    } else if (blk == 1) {
      float a = 0; for (int h = 0; h < 256; ++h) a += Wfc[h * 256 + tid] * Wf2[h];
      vv[256 + tid] = a;
    } else if (blk == 2) {
      if (tid == 0) { float a = 0; for (int h = 0; h < 256; ++h) a += bfc[h] * Wa[256 + h]; vv[512] = a; }
      if (tid == 1) { float a = bf2_[0]; for (int h = 0; h < 256; ++h) a += bfc[h] * Wf2[h]; vv[513] = a; }
    } else if (blk < 7) {
      int j = (blk - 3) * 256 + tid;
      float a = bihd[j] + bhhd[j];
      for (int h = 0; h < 256; ++h) a += Wihd[j * 257 + 1 + h] * bfc[h];
      vv[576 + j] = a;
    }
  } else if (bid < 72) {
    const int wb = bid - 8;
    __shared__ float sR[16][256];
    for (int i = tid; i < 16 * 256; i += 256) {
      int r = i >> 8, h = i & 255;
      sR[r][h] = Wihd[(wb * 16 + r) * 257 + 1 + h];
    }
    __syncthreads();
    const int k = tid;
    float a[16];
#pragma unroll
    for (int r = 0; r < 16; ++r) a[r] = 0.f;
    for (int h = 0; h < 256; ++h) {
      float wv = Wfc[h * 256 + k];
#pragma unroll
      for (int r = 0; r < 16; ++r) a[r] += sR[r][h] * wv;
    }
#pragma unroll
    for (int r = 0; r < 16; ++r) wxd[(wb * 16 + r) * 256 + k] = a[r];
  } else {
    int i = (bid - 72) * 256 + tid;
    if (i < 16384) {                 // wall ks0..3
      int l = i & 63, f = (i >> 6) & 63, ks = i >> 12;
      int q = f & 3, p = (f >> 2) & 1, w = f >> 3;
      int g = l >> 4, c16 = l & 15;
      int row = 256 * q + 16 * (w + 8 * p) + c16;
      f16x8 v;
#pragma unroll
      for (int jj = 0; jj < 8; ++jj) v[jj] = (f16)Whh[row * 256 + ks * 32 + 8 * g + jj];
      ((f16x8*)wall)[i] = v;
    } else if (i < 24576) {          // w67 ks6,7  (2 copies)
      int j = i - 16384;
      int l = j & 63, f = (j >> 6) & 63, ks = 6 + (j >> 12);
      int q = f & 3, p = (f >> 2) & 1, w = f >> 3;
      int g = l >> 4, c16 = l & 15;
      int row = 256 * q + 16 * (w + 8 * p) + c16;
      f16x8 v;
#pragma unroll
      for (int jj = 0; jj < 8; ++jj) v[jj] = (f16)Whh[row * 256 + ks * 32 + 8 * g + jj];
      ((f16x8*)w67)[j] = v;
      ((f16x8*)w67)[j + 8192] = v;
    } else if (i < 28672) {          // xb (2 copies)
      int j = i - 24576;
      int l = j & 63, f = (j >> 6) & 63;
      int q = f & 3, p = (f >> 2) & 1, w = f >> 3;
      int g = l >> 4, c16 = l & 15;
      int row = 256 * q + 16 * (w + 8 * p) + c16;
      f16x8 v;
#pragma unroll
      for (int jj = 0; jj < 8; ++jj) {
        int k = 8 * g + jj;
        float val = (k < 16) ? Wih[row * 16 + k] : (k == 16 ? (bih[row] + bhh[row]) : 0.f);
        v[jj] = (f16)val;
      }
      ((f16x8*)xb)[j] = v;
      ((f16x8*)xb)[j + 4096] = v;
    }
  }
}

// ---------------- x A-fragment prepass (coalesced) ----------------
__global__ __launch_bounds__(128) void k_xf(const float* __restrict__ src1,
    const float* __restrict__ src2, const float* __restrict__ Wc, const float* __restrict__ bc,
    f16* __restrict__ xf) {
  const int b = blockIdx.x >> 4, tc = blockIdx.x & 15;
  const int t = tc * 128 + threadIdx.x;
  f16x8 v0, v1, v2, v3;
#pragma unroll
  for (int f = 0; f < 8; ++f)  v0[f] = (f16)src1[((size_t)b * T_ + t) * 15 + f];
#pragma unroll
  for (int f = 0; f < 7; ++f)  v1[f] = (f16)src1[((size_t)b * T_ + t) * 15 + 8 + f];
  float s = bc[0];
#pragma unroll
  for (int u = 0; u < 8; ++u) s += src2[((size_t)b * T_ + t) * 8 + u] * Wc[u];
  v1[7] = (f16)s;
  v2 = (f16x8){(f16)1.f, (f16)0.f, (f16)0.f, (f16)0.f, (f16)0.f, (f16)0.f, (f16)0.f, (f16)0.f};
  v3 = (f16x8){(f16)0.f, (f16)0.f, (f16)0.f, (f16)0.f, (f16)0.f, (f16)0.f, (f16)0.f, (f16)0.f};
  f16* o = xf + (((size_t)t * 8 + (b >> 4)) * 16 + (b & 15)) * 32;
  *(f16x8*)(o) = v0; *(f16x8*)(o + 8) = v1; *(f16x8*)(o + 16) = v2; *(f16x8*)(o + 24) = v3;
}

// ---------------- encoder: R10 structure + fused eproj/token/s0 ----------
__global__ __launch_bounds__(512, 2) void k_enc(const float* __restrict__ Whh,
    const f16* __restrict__ wall, const f16* __restrict__ w67, const f16* __restrict__ xb,
    const f16* __restrict__ xf, const float* __restrict__ vv, const float* __restrict__ Wa,
    f16* __restrict__ outs, float* __restrict__ hh0, float* __restrict__ cc0,
    float* __restrict__ eproj, float* __restrict__ inp_buf, float* __restrict__ s_acc) {
  const int blk = blockIdx.x, tid = threadIdx.x;
  const int w = tid >> 6, l = tid & 63, g = l >> 4, c16 = l & 15;
  __shared__ f16x8 Wl[8192];                      // ks4,5: [((ksl*8+w)*2+p)*4+q][lane] = 128 KiB
  __shared__ __align__(16) f16 hbuf[2][16 * 264]; // ping-pong h[b][jh], stride 264
  __shared__ __align__(16) float sV[256], sV2[256], sWaH[256];

  // LDS-resident weights ks4,5 (setup-only f32 read)
#pragma unroll
  for (int ksl = 0; ksl < 2; ++ksl)
#pragma unroll
    for (int p = 0; p < 2; ++p)
#pragma unroll
      for (int q = 0; q < 4; ++q) {
        const int row = 256 * q + 16 * (w + 8 * p) + c16;
        const float* s = Whh + row * 256 + (4 + ksl) * 32 + 8 * g;
        f16x8 v;
#pragma unroll
        for (int jj = 0; jj < 8; ++jj) v[jj] = (f16)s[jj];
        Wl[((((ksl * 8 + w) * 2 + p) * 4 + q)) * 64 + l] = v;
      }
  // ks0..3 weights from f16 fragment image
  const f16x8* wallv = (const f16x8*)wall;
  f16x8 wf[4][2][4];
#pragma unroll
  for (int ks = 0; ks < 4; ++ks)
#pragma unroll
    for (int p = 0; p < 2; ++p)
#pragma unroll
      for (int q = 0; q < 4; ++q)
        wf[ks][p][q] = wallv[(size_t)(ks * 64 + w * 8 + p * 4 + q) * 64 + l];
  for (int i = tid; i < 16 * 264; i += 512) hbuf[0][i] = (f16)0.f;
  for (int i = tid; i < 256; i += 512) {
    sV[i] = vv[i]; sV2[i] = vv[256 + i]; sWaH[i] = Wa[i];
  }
  const float c0 = vv[512], c2 = vv[513];
  __syncthreads();

  f32x4 cst[2];
  cst[0] = (f32x4){0.f, 0.f, 0.f, 0.f};
  cst[1] = (f32x4){0.f, 0.f, 0.f, 0.f};

  const f16x8* w67v = (const f16x8*)w67;
  const f16x8* xbv = (const f16x8*)xb;
  const int fb = w * 8;
  const int obl = tid >> 5, ou = tid & 31;        // outs-writer mapping

#define LDA(ks) (*(const f16x8*)(hb + c16 * 264 + (ks) * 32 + 8 * g))
#define MF8(A, BB) \
  { _Pragma("unroll") for (int p = 0; p < 2; ++p) \
    _Pragma("unroll") for (int q = 0; q < 4; ++q) \
      acc[p][q] = __builtin_amdgcn_mfma_f32_16x16x32_f16((A), BB[p][q], acc[p][q], 0, 0, 0); }
#define STAGE(SRC) \
  { _Pragma("unroll") for (int p = 0; p < 2; ++p) \
    _Pragma("unroll") for (int q = 0; q < 4; ++q) \
      st[p][q] = (SRC)[(size_t)(fb + p * 4 + q) * 64 + l]; }

  f16x8 xac = *(const f16x8*)(xf + ((size_t)blk * 16 + c16) * 32 + 8 * g);   // t=0

  for (int t = 0; t < T_; ++t) {
    const int cp = t & 1;
    const f16* hb = hbuf[cp];
    const f16x8* sx = xbv + (size_t)cp * 4096;
    const f16x8* s6 = w67v + (size_t)cp * 8192;
    const f16x8* s7 = s6 + 4096;

    f16x8 st[2][4];
    STAGE(sx);
    const int tn = (t + 1 < T_) ? (t + 1) : t;
    const f16x8 xan = *(const f16x8*)(xf + (((size_t)tn * 8 + blk) * 16 + c16) * 32 + 8 * g);

    // deferred coalesced outs write + fused eproj for h(t-1), overlap under MFMAs
    if (t > 0) {
      const f16x8 hv = *(const f16x8*)(hb + obl * 264 + ou * 8);
      *(f16x8*)(outs + ((size_t)(blk * 16 + obl) * T_ + (t - 1)) * H_ + ou * 8) = hv;
#pragma unroll
      for (int b2 = 0; b2 < 2; ++b2) {
        const int bb2 = 2 * w + b2;
        const f16x4 h4 = *(const f16x4*)(hb + bb2 * 264 + l * 4);
        const float4 v4 = *(const float4*)&sV[l * 4];
        float s = (float)h4[0] * v4.x + (float)h4[1] * v4.y
                + (float)h4[2] * v4.z + (float)h4[3] * v4.w;
#pragma unroll
        for (int off = 32; off > 0; off >>= 1) s += __shfl_down(s, off);
        if (l == 0) eproj[(size_t)(blk * 16 + bb2) * T_ + (t - 1)] = s + c0;
      }
    }

    f32x4 acc[2][4];
#pragma unroll
    for (int p = 0; p < 2; ++p)
#pragma unroll
      for (int q = 0; q < 4; ++q) acc[p][q] = (f32x4){0.f, 0.f, 0.f, 0.f};

    { const f16x8 a = LDA(0); MF8(a, wf[0]); }
    { const f16x8 a = LDA(1); MF8(a, wf[1]); }
    { const f16x8 a = LDA(2); MF8(a, wf[2]); }
    MF8(xac, st);
    STAGE(s6);
    { const f16x8 a = LDA(3); MF8(a, wf[3]); }
    { const f16x8 a = LDA(4);
#pragma unroll
      for (int p = 0; p < 2; ++p)
#pragma unroll
        for (int q = 0; q < 4; ++q) {
          const f16x8 bb = Wl[(((0 * 8 + w) * 2 + p) * 4 + q) * 64 + l];
          acc[p][q] = __builtin_amdgcn_mfma_f32_16x16x32_f16(a, bb, acc[p][q], 0, 0, 0);
        } }
    { const f16x8 a = LDA(6); MF8(a, st); }
    STAGE(s7);
    { const f16x8 a = LDA(5);
#pragma unroll
      for (int p = 0; p < 2; ++p)
#pragma unroll
        for (int q = 0; q < 4; ++q) {
          const f16x8 bb = Wl[(((1 * 8 + w) * 2 + p) * 4 + q) * 64 + l];
          acc[p][q] = __builtin_amdgcn_mfma_f32_16x16x32_f16(a, bb, acc[p][q], 0, 0, 0);
        } }
    { const f16x8 a = LDA(7); MF8(a, st); }

    // epilogue: LSTM cell
    f16* hw = hbuf[cp ^ 1];
#pragma unroll
    for (int p = 0; p < 2; ++p) {
      const int jh = 16 * (w + 8 * p) + c16;
#pragma unroll
      for (int r = 0; r < 4; ++r) {
        const float iv = acc[p][0][r], fv = acc[p][1][r], gv = acc[p][2][r], ov = acc[p][3][r];
        const float cn = sigf(fv) * cst[p][r] + sigf(iv) * tanh_(gv);
        cst[p][r] = cn;
        const float hn = sigf(ov) * tanh_(cn);
        const int bl = 4 * g + r;
        hw[bl * 264 + jh] = (f16)hn;
        if (t == T_ - 1) {
          hh0[(blk * 16 + bl) * H_ + jh] = hn;
          cc0[(blk * 16 + bl) * H_ + jh] = cn;
        }
      }
    }
    xac = xan;
    __syncthreads();
  }
  // final: outs row T-1, eproj[T-1], token, s0 — h(T-1) lives in hbuf[0] (T even)
  {
    const f16* hb0 = hbuf[0];
    const f16x8 hv = *(const f16x8*)(hb0 + obl * 264 + ou * 8);
    *(f16x8*)(outs + ((size_t)(blk * 16 + obl) * T_ + (T_ - 1)) * H_ + ou * 8) = hv;
#pragma unroll
    for (int b2 = 0; b2 < 2; ++b2) {
      const int bb2 = 2 * w + b2;
      const f16x4 h4 = *(const f16x4*)(hb0 + bb2 * 264 + l * 4);
      const float4 v4 = *(const float4*)&sV[l * 4];
      const float4 u4 = *(const float4*)&sV2[l * 4];
      const float4 a4 = *(const float4*)&sWaH[l * 4];
      float se = (float)h4[0] * v4.x + (float)h4[1] * v4.y + (float)h4[2] * v4.z + (float)h4[3] * v4.w;
      float st_ = (float)h4[0] * u4.x + (float)h4[1] * u4.y + (float)h4[2] * u4.z + (float)h4[3] * u4.w;
      float sa = (float)h4[0] * a4.x + (float)h4[1] * a4.y + (float)h4[2] * a4.z + (float)h4[3] * a4.w;
#pragma unroll
      for (int off = 32; off > 0; off >>= 1) {
        se += __shfl_down(se, off);
        st_ += __shfl_down(st_, off);
        sa += __shfl_down(sa, off);
      }
      if (l == 0) {
        const int b = blk * 16 + bb2;
        eproj[(size_t)b * T_ + (T_ - 1)] = se + c0;
        inp_buf[b] = st_ + c2;
        s_acc[b] = sa;
      }
    }
  }
#undef LDA
#undef MF8
#undef STAGE
}

// ---------------- attention: ctx' = softmax(tanh(s+eproj)) @ outs ----------------
__global__ void k_attn(int d, const float* __restrict__ eproj, const f16* __restrict__ outs,
                       const float* __restrict__ s_acc, float* __restrict__ ctxacc,
                       const float* __restrict__ pred_acc, float* __restrict__ inp_buf,
                       float* __restrict__ dout, const float* __restrict__ bo) {
  const int b = blockIdx.x >> 4, ch = blockIdx.x & 15;
  const int k = threadIdx.x;
  if (d > 0 && ch == 0 && k == 0) {
    float pv = pred_acc[(d - 1) * B_ + b] + bo[0];
    inp_buf[d * B_ + b] = pv;
    dout[b * TRG_ + (d - 1)] = pv;
  }
  __shared__ float swt[128];
  const float s = s_acc[d * B_ + b];
  if (k < 128) {
    float e = eproj[b * T_ + ch * 128 + k];
    swt[k] = __expf(tanh_(s + e));
  }
  __syncthreads();
  float acc = 0.f;
  const f16* op = outs + ((size_t)b * T_ + ch * 128) * H_ + k;
#pragma unroll 8
  for (int tt = 0; tt < 128; ++tt) acc += swt[tt] * (float)op[tt * H_];
  atomicAdd(&ctxacc[((size_t)d * B_ + b) * 257 + k], acc);
  if (k == 0) {
    float sw = 0;
    for (int tt = 0; tt < 128; ++tt) sw += swt[tt];
    atomicAdd(&ctxacc[((size_t)d * B_ + b) * 257 + 256], sw);
  }
}

// ---------------- decoder LSTM cell (128 blocks: 64 jb x 2 batch-halves, b128 dot) ----------
__global__ __launch_bounds__(512) void k_cell(int d, const float* __restrict__ wxd,
    const float* __restrict__ Whhd, const float* __restrict__ Wihd, const float* __restrict__ vv,
    const float* __restrict__ ctxacc, const float* __restrict__ inp_buf,
    float* __restrict__ hh, float* __restrict__ cc,
    float* __restrict__ s_acc, float* __restrict__ pred_acc,
    const float* __restrict__ Wa, const float* __restrict__ Wo) {
  const int jb = blockIdx.x & 63, half = blockIdx.x >> 6;
  const int tid = threadIdx.x;
  const int rr = tid & 15, bb = tid >> 4;
  __shared__ __align__(16) float sW[16][516];
  __shared__ __align__(16) float sX[32][516];
  __shared__ float sG[32][17];
  __shared__ float sden[32], sinp[32];
  __shared__ float scol0[16], sbias[16];
  const float* bdp = vv + 576;
  for (int idx = tid; idx < 16 * 512; idx += 512) {
    int r2 = idx >> 9, k2 = idx & 511;
    int row = 256 * (r2 >> 2) + 4 * jb + (r2 & 3);
    sW[r2][k2] = (k2 < 256) ? wxd[row * 256 + k2] : Whhd[row * 256 + (k2 - 256)];
  }
  if (tid < 16) {
    int row = 256 * (tid >> 2) + 4 * jb + (tid & 3);
    scol0[tid] = Wihd[row * 257];
    sbias[tid] = bdp[row];
  }
  const float* hh_r = hh + (d & 1) * B_ * H_;
  float* hh_w = hh + ((d + 1) & 1) * B_ * H_;
  for (int bc2 = 0; bc2 < 2; ++bc2) {
    const int bc = half * 2 + bc2;
    __syncthreads();
    if (tid < 32) {
      int b = bc * 32 + tid;
      sden[tid] = 1.0f / ctxacc[((size_t)d * B_ + b) * 257 + 256];
      sinp[tid] = inp_buf[d * B_ + b];
    }
    __syncthreads();
    for (int idx = tid; idx < 32 * 512; idx += 512) {
      int b2 = idx >> 9, k2 = idx & 511;
      int b = bc * 32 + b2;
      sX[b2][k2] = (k2 < 256) ? ctxacc[((size_t)d * B_ + b) * 257 + k2] * sden[b2]
                              : hh_r[b * 256 + (k2 - 256)];
    }
    __syncthreads();
    {
      float a = sbias[rr] + scol0[rr] * sinp[bb];
      const float4* wr4 = (const float4*)sW[rr];
      const float4* xr4 = (const float4*)sX[bb];
      for (int k4 = 0; k4 < 128; ++k4) {
        const float4 wv = wr4[k4], xv = xr4[k4];
        a += wv.x * xv.x + wv.y * xv.y + wv.z * xv.z + wv.w * xv.w;
      }
      sG[bb][rr] = a;
    }
    __syncthreads();
    if (rr < 4) {
      int b = bc * 32 + bb;
      int jh = 4 * jb + rr;
      float iv = sG[bb][rr], fv = sG[bb][4 + rr], gv = sG[bb][8 + rr], ov = sG[bb][12 + rr];
      float cn = sigf(fv) * cc[b * H_ + jh] + sigf(iv) * tanh_(gv);
      cc[b * H_ + jh] = cn;
      float hn = sigf(ov) * tanh_(cn);
      hh_w[b * H_ + jh] = hn;
      atomicAdd(&s_acc[(d + 1) * B_ + b], hn * Wa[jh]);
      atomicAdd(&pred_acc[d * B_ + b], hn * Wo[jh]);
    }
  }
}

__global__ void k_finish(const float* __restrict__ pred_acc, const float* __restrict__ bo,
                         float* __restrict__ dout) {
  int b = threadIdx.x;
  if (b < B_) dout[b * TRG_ + (TRG_ - 1)] = pred_acc[(TRG_ - 1) * B_ + b] + bo[0];
}

// ---------------- launch ----------------
extern "C" void kernel_launch(void* const* d_in, const int* in_sizes, int n_in,
                              void* d_out, int out_size, void* d_ws, size_t ws_size,
                              hipStream_t stream) {
  (void)in_sizes; (void)n_in; (void)out_size;
  float* dout = (float*)d_out;
  if (ws_size < WS_NEED) {
    k_wsfail<<<1, 1, 0, stream>>>(dout, (float)(ws_size >> 20));
    return;
  }
  const float* src1 = (const float*)d_in[0];
  const float* src2 = (const float*)d_in[1];
  const float* Wc   = (const float*)d_in[2];
  const float* bc   = (const float*)d_in[3];
  const float* Wihe = (const float*)d_in[4];
  const float* Whhe = (const float*)d_in[5];
  const float* bihe = (const float*)d_in[6];
  const float* bhhe = (const float*)d_in[7];
  const float* Wfc  = (const float*)d_in[8];
  const float* bfc  = (const float*)d_in[9];
  const float* Wf2  = (const float*)d_in[10];
  const float* bf2  = (const float*)d_in[11];
  const float* Wa   = (const float*)d_in[12];
  const float* Wihd = (const float*)d_in[13];
  const float* Whhd = (const float*)d_in[14];
  const float* bihd = (const float*)d_in[15];
  const float* bhhd = (const float*)d_in[16];
  const float* Wo   = (const float*)d_in[17];
  const float* bo   = (const float*)d_in[18];

  char* ws = (char*)d_ws;
  f16*   xf    = (f16*)(ws + XF_OFF);
  f16*   outs  = (f16*)(ws + OUTS_OFF);
  float* eproj = (float*)(ws + EPROJ_OFF);
  float* hh    = (float*)(ws + HH_OFF);
  float* cc    = (float*)(ws + CC_OFF);
  float* wxd   = (float*)(ws + WXD_OFF);
  float* vv    = (float*)(ws + VV_OFF);
  f16*   wall  = (f16*)(ws + WALL_OFF);
  f16*   w67   = (f16*)(ws + W67_OFF);
  f16*   xb    = (f16*)(ws + XB_OFF);
  float* zb    = (float*)(ws + ZERO_OFF);
  float* ctxacc   = zb;
  float* s_acc    = zb + CTX_CNT;
  float* pred_acc = s_acc + SAC_CNT;
  float* inp_buf  = pred_acc + PRD_CNT;

  k_zero<<<256, 256, 0, stream>>>(zb, ZERO_CNT);
  k_setup<<<184, 256, 0, stream>>>(Wfc, Wa, Wf2, bf2, bfc, bihd, bhhd, Wihd,
                                   Whhe, Wihe, bihe, bhhe, vv, wxd, wall, w67, xb);
  k_xf<<<B_ * 16, 128, 0, stream>>>(src1, src2, Wc, bc, xf);
  k_enc<<<NBLK, 512, 0, stream>>>(Whhe, wall, w67, xb, xf, vv, Wa, outs, hh, cc,
                                  eproj, inp_buf, s_acc);
  for (int d = 0; d < TRG_; ++d) {
    k_attn<<<B_ * 16, 256, 0, stream>>>(d, eproj, outs, s_acc, ctxacc, pred_acc, inp_buf, dout, bo);
    k_cell<<<128, 512, 0, stream>>>(d, wxd, Whhd, Wihd, vv, ctxacc, inp_buf, hh, cc, s_acc, pred_acc, Wa, Wo);
  }
  k_finish<<<1, 128, 0, stream>>>(pred_acc, bo, dout);
}

// Round 13
// 10999.142 us; speedup vs baseline: 1.4409x; 1.4409x over previous
//
#include <hip/hip_runtime.h>
#include <hip/hip_fp16.h>

typedef __attribute__((ext_vector_type(4))) float f32x4;
typedef _Float16 f16;
typedef __attribute__((ext_vector_type(2))) _Float16 f16x2;
typedef __attribute__((ext_vector_type(4))) _Float16 f16x4;
typedef __attribute__((ext_vector_type(8))) _Float16 f16x8;

#define DEV static __device__ __forceinline__

constexpr int B_ = 128, T_ = 2048, H_ = 256, TRG_ = 24;
constexpr int NBLK = 8;   // encoder blocks, 16 batches each

// ---------------- workspace layout (~150 MiB) ----------------
constexpr size_t XF_OFF   = 0;                                   // x A-fragments [t][blk][bb][32] f16
constexpr size_t XF_BYTES = (size_t)T_ * NBLK * 16 * 32 * 2;     // 16 MiB
constexpr size_t OUTS_OFF = XF_OFF + XF_BYTES;
constexpr size_t OUTS_BYTES = (size_t)B_ * T_ * H_ * 2;          // 128 MiB f16
constexpr size_t EPROJ_OFF = OUTS_OFF + OUTS_BYTES;
constexpr size_t EPROJ_BYTES = (size_t)B_ * T_ * 4;              // 1 MiB
constexpr size_t HH_OFF = EPROJ_OFF + EPROJ_BYTES;               // enc final h (f32)
constexpr size_t HH_BYTES = 2ull * B_ * H_ * 4;
constexpr size_t CC_OFF = HH_OFF + HH_BYTES;                     // enc final c (f32)
constexpr size_t CC_BYTES = (size_t)B_ * H_ * 4;
constexpr size_t WXD_OFF = CC_OFF + CC_BYTES;                    // Wih_d[:,1:] @ Wfc (1024x256) f32
constexpr size_t WXD_BYTES = 1024ull * 256 * 4;
constexpr size_t VV_OFF = WXD_OFF + WXD_BYTES;
constexpr size_t VV_BYTES = 8192;
constexpr size_t WALL_OFF = VV_OFF + VV_BYTES;                   // enc weights ks0-3 image (f16 frags)
constexpr size_t WALL_BYTES = 16384ull * 16;                     // 256 KiB
constexpr size_t W67_OFF = WALL_OFF + WALL_BYTES;                // streamed enc weights ks6,7 (x2 copies)
constexpr size_t W67_BYTES = 2ull * 8192 * 16;                   // 256 KiB
constexpr size_t XB_OFF = W67_OFF + W67_BYTES;                   // streamed x weights (x2 copies)
constexpr size_t XB_BYTES = 2ull * 4096 * 16;                    // 128 KiB
constexpr size_t WDT_OFF = XB_OFF + XB_BYTES;                    // decoder weights T: [k512][j1024] f16
constexpr size_t WDT_BYTES = 512ull * 1024 * 2;                  // 1 MiB
constexpr size_t WS_NEED = WDT_OFF + WDT_BYTES + 1024;

// ---------------- helpers ----------------
DEV float sigf(float x)  { return 1.0f / (1.0f + __expf(-x)); }
DEV float tanh_(float x) { return 1.0f - 2.0f / (__expf(2.0f * x) + 1.0f); }

__global__ void k_wsfail(float* __restrict__ dout, float mb) { dout[0] = 1e6f + mb; }

// ---------------- merged setup: vv (blk<8), wxd (blk<72), enc weight images (else) -------------
__global__ void k_setup(const float* __restrict__ Wfc, const float* __restrict__ Wa,
                        const float* __restrict__ Wf2, const float* __restrict__ bf2_,
                        const float* __restrict__ bfc, const float* __restrict__ bihd,
                        const float* __restrict__ bhhd, const float* __restrict__ Wihd,
                        const float* __restrict__ Whh, const float* __restrict__ Wih,
                        const float* __restrict__ bih, const float* __restrict__ bhh,
                        float* __restrict__ vv, float* __restrict__ wxd,
                        f16* __restrict__ wall, f16* __restrict__ w67, f16* __restrict__ xb) {
  const int bid = blockIdx.x, tid = threadIdx.x;
  if (bid < 8) {
    const int blk = bid;
    if (blk == 0) {
      float a = 0; for (int h = 0; h < 256; ++h) a += Wfc[h * 256 + tid] * Wa[256 + h];
      vv[tid] = a;
    } else if (blk == 1) {
      float a = 0; for (int h = 0; h < 256; ++h) a += Wfc[h * 256 + tid] * Wf2[h];
      vv[256 + tid] = a;
    } else if (blk == 2) {
      if (tid == 0) { float a = 0; for (int h = 0; h < 256; ++h) a += bfc[h] * Wa[256 + h]; vv[512] = a; }
      if (tid == 1) { float a = bf2_[0]; for (int h = 0; h < 256; ++h) a += bfc[h] * Wf2[h]; vv[513] = a; }
    } else if (blk < 7) {
      int j = (blk - 3) * 256 + tid;
      float a = bihd[j] + bhhd[j];
      for (int h = 0; h < 256; ++h) a += Wihd[j * 257 + 1 + h] * bfc[h];
      vv[576 + j] = a;
    }
  } else if (bid < 72) {
    const int wb = bid - 8;
    __shared__ float sR[16][256];
    for (int i = tid; i < 16 * 256; i += 256) {
      int r = i >> 8, h = i & 255;
      sR[r][h] = Wihd[(wb * 16 + r) * 257 + 1 + h];
    }
    __syncthreads();
    const int k = tid;
    float a[16];
#pragma unroll
    for (int r = 0; r < 16; ++r) a[r] = 0.f;
    for (int h = 0; h < 256; ++h) {
      float wv = Wfc[h * 256 + k];
#pragma unroll
      for (int r = 0; r < 16; ++r) a[r] += sR[r][h] * wv;
    }
#pragma unroll
    for (int r = 0; r < 16; ++r) wxd[(wb * 16 + r) * 256 + k] = a[r];
  } else {
    int i = (bid - 72) * 256 + tid;
    if (i < 16384) {                 // wall ks0..3
      int l = i & 63, f = (i >> 6) & 63, ks = i >> 12;
      int q = f & 3, p = (f >> 2) & 1, w = f >> 3;
      int g = l >> 4, c16 = l & 15;
      int row = 256 * q + 16 * (w + 8 * p) + c16;
      f16x8 v;
#pragma unroll
      for (int jj = 0; jj < 8; ++jj) v[jj] = (f16)Whh[row * 256 + ks * 32 + 8 * g + jj];
      ((f16x8*)wall)[i] = v;
    } else if (i < 24576) {          // w67 ks6,7  (2 copies)
      int j = i - 16384;
      int l = j & 63, f = (j >> 6) & 63, ks = 6 + (j >> 12);
      int q = f & 3, p = (f >> 2) & 1, w = f >> 3;
      int g = l >> 4, c16 = l & 15;
      int row = 256 * q + 16 * (w + 8 * p) + c16;
      f16x8 v;
#pragma unroll
      for (int jj = 0; jj < 8; ++jj) v[jj] = (f16)Whh[row * 256 + ks * 32 + 8 * g + jj];
      ((f16x8*)w67)[j] = v;
      ((f16x8*)w67)[j + 8192] = v;
    } else if (i < 28672) {          // xb (2 copies)
      int j = i - 24576;
      int l = j & 63, f = (j >> 6) & 63;
      int q = f & 3, p = (f >> 2) & 1, w = f >> 3;
      int g = l >> 4, c16 = l & 15;
      int row = 256 * q + 16 * (w + 8 * p) + c16;
      f16x8 v;
#pragma unroll
      for (int jj = 0; jj < 8; ++jj) {
        int k = 8 * g + jj;
        float val = (k < 16) ? Wih[row * 16 + k] : (k == 16 ? (bih[row] + bhh[row]) : 0.f);
        v[jj] = (f16)val;
      }
      ((f16x8*)xb)[j] = v;
      ((f16x8*)xb)[j + 4096] = v;
    }
  }
}

// ---------------- decoder weight transpose: wdT[k][j] (k<256: wxd, else Whhd), f16 ------------
__global__ void k_wdt(const float* __restrict__ wxd, const float* __restrict__ Whhd,
                      f16* __restrict__ wdT) {
  const int k = blockIdx.x, tid = threadIdx.x;
#pragma unroll
  for (int j4 = 0; j4 < 4; ++j4) {
    const int j = j4 * 256 + tid;
    const float val = (k < 256) ? wxd[j * 256 + k] : Whhd[j * 256 + (k - 256)];
    wdT[(size_t)k * 1024 + j] = (f16)val;
  }
}

// ---------------- x A-fragment prepass (coalesced) ----------------
__global__ __launch_bounds__(128) void k_xf(const float* __restrict__ src1,
    const float* __restrict__ src2, const float* __restrict__ Wc, const float* __restrict__ bc,
    f16* __restrict__ xf) {
  const int b = blockIdx.x >> 4, tc = blockIdx.x & 15;
  const int t = tc * 128 + threadIdx.x;
  f16x8 v0, v1, v2, v3;
#pragma unroll
  for (int f = 0; f < 8; ++f)  v0[f] = (f16)src1[((size_t)b * T_ + t) * 15 + f];
#pragma unroll
  for (int f = 0; f < 7; ++f)  v1[f] = (f16)src1[((size_t)b * T_ + t) * 15 + 8 + f];
  float s = bc[0];
#pragma unroll
  for (int u = 0; u < 8; ++u) s += src2[((size_t)b * T_ + t) * 8 + u] * Wc[u];
  v1[7] = (f16)s;
  v2 = (f16x8){(f16)1.f, (f16)0.f, (f16)0.f, (f16)0.f, (f16)0.f, (f16)0.f, (f16)0.f, (f16)0.f};
  v3 = (f16x8){(f16)0.f, (f16)0.f, (f16)0.f, (f16)0.f, (f16)0.f, (f16)0.f, (f16)0.f, (f16)0.f};
  f16* o = xf + (((size_t)t * 8 + (b >> 4)) * 16 + (b & 15)) * 32;
  *(f16x8*)(o) = v0; *(f16x8*)(o + 8) = v1; *(f16x8*)(o + 16) = v2; *(f16x8*)(o + 24) = v3;
}

// ---------------- encoder: R10 structure (best measured) ----------
__global__ __launch_bounds__(512, 2) void k_enc(const float* __restrict__ Whh,
    const f16* __restrict__ wall, const f16* __restrict__ w67, const f16* __restrict__ xb,
    const f16* __restrict__ xf, f16* __restrict__ outs,
    float* __restrict__ hh0, float* __restrict__ cc0) {
  const int blk = blockIdx.x, tid = threadIdx.x;
  const int w = tid >> 6, l = tid & 63, g = l >> 4, c16 = l & 15;
  __shared__ f16x8 Wl[8192];                      // ks4,5: [((ksl*8+w)*2+p)*4+q][lane] = 128 KiB
  __shared__ __align__(16) f16 hbuf[2][16 * 264]; // ping-pong h[b][jh], stride 264

  // LDS-resident weights ks4,5 (setup-only f32 read)
#pragma unroll
  for (int ksl = 0; ksl < 2; ++ksl)
#pragma unroll
    for (int p = 0; p < 2; ++p)
#pragma unroll
      for (int q = 0; q < 4; ++q) {
        const int row = 256 * q + 16 * (w + 8 * p) + c16;
        const float* s = Whh + row * 256 + (4 + ksl) * 32 + 8 * g;
        f16x8 v;
#pragma unroll
        for (int jj = 0; jj < 8; ++jj) v[jj] = (f16)s[jj];
        Wl[((((ksl * 8 + w) * 2 + p) * 4 + q)) * 64 + l] = v;
      }
  // ks0..3 weights from f16 fragment image
  const f16x8* wallv = (const f16x8*)wall;
  f16x8 wf[4][2][4];
#pragma unroll
  for (int ks = 0; ks < 4; ++ks)
#pragma unroll
    for (int p = 0; p < 2; ++p)
#pragma unroll
      for (int q = 0; q < 4; ++q)
        wf[ks][p][q] = wallv[(size_t)(ks * 64 + w * 8 + p * 4 + q) * 64 + l];
  for (int i = tid; i < 16 * 264; i += 512) hbuf[0][i] = (f16)0.f;
  __syncthreads();

  f32x4 cst[2];
  cst[0] = (f32x4){0.f, 0.f, 0.f, 0.f};
  cst[1] = (f32x4){0.f, 0.f, 0.f, 0.f};

  const f16x8* w67v = (const f16x8*)w67;
  const f16x8* xbv = (const f16x8*)xb;
  const int fb = w * 8;
  const int obl = tid >> 5, ou = tid & 31;        // outs-writer mapping

#define LDA(ks) (*(const f16x8*)(hb + c16 * 264 + (ks) * 32 + 8 * g))
#define MF8(A, BB) \
  { _Pragma("unroll") for (int p = 0; p < 2; ++p) \
    _Pragma("unroll") for (int q = 0; q < 4; ++q) \
      acc[p][q] = __builtin_amdgcn_mfma_f32_16x16x32_f16((A), BB[p][q], acc[p][q], 0, 0, 0); }
#define STAGE(SRC) \
  { _Pragma("unroll") for (int p = 0; p < 2; ++p) \
    _Pragma("unroll") for (int q = 0; q < 4; ++q) \
      st[p][q] = (SRC)[(size_t)(fb + p * 4 + q) * 64 + l]; }

  f16x8 xac = *(const f16x8*)(xf + ((size_t)blk * 16 + c16) * 32 + 8 * g);   // t=0

  for (int t = 0; t < T_; ++t) {
    const int cp = t & 1;
    const f16* hb = hbuf[cp];
    const f16x8* sx = xbv + (size_t)cp * 4096;
    const f16x8* s6 = w67v + (size_t)cp * 8192;
    const f16x8* s7 = s6 + 4096;

    f16x8 st[2][4];
    STAGE(sx);
    const int tn = (t + 1 < T_) ? (t + 1) : t;
    const f16x8 xan = *(const f16x8*)(xf + (((size_t)tn * 8 + blk) * 16 + c16) * 32 + 8 * g);

    // coalesced outs write of h(t-1), drains under MFMAs
    if (t > 0) {
      const f16x8 hv = *(const f16x8*)(hb + obl * 264 + ou * 8);
      *(f16x8*)(outs + ((size_t)(blk * 16 + obl) * T_ + (t - 1)) * H_ + ou * 8) = hv;
    }

    f32x4 acc[2][4];
#pragma unroll
    for (int p = 0; p < 2; ++p)
#pragma unroll
      for (int q = 0; q < 4; ++q) acc[p][q] = (f32x4){0.f, 0.f, 0.f, 0.f};

    { const f16x8 a = LDA(0); MF8(a, wf[0]); }
    { const f16x8 a = LDA(1); MF8(a, wf[1]); }
    { const f16x8 a = LDA(2); MF8(a, wf[2]); }
    MF8(xac, st);
    STAGE(s6);
    { const f16x8 a = LDA(3); MF8(a, wf[3]); }
    { const f16x8 a = LDA(4);
#pragma unroll
      for (int p = 0; p < 2; ++p)
#pragma unroll
        for (int q = 0; q < 4; ++q) {
          const f16x8 bb = Wl[(((0 * 8 + w) * 2 + p) * 4 + q) * 64 + l];
          acc[p][q] = __builtin_amdgcn_mfma_f32_16x16x32_f16(a, bb, acc[p][q], 0, 0, 0);
        } }
    { const f16x8 a = LDA(6); MF8(a, st); }
    STAGE(s7);
    { const f16x8 a = LDA(5);
#pragma unroll
      for (int p = 0; p < 2; ++p)
#pragma unroll
        for (int q = 0; q < 4; ++q) {
          const f16x8 bb = Wl[(((1 * 8 + w) * 2 + p) * 4 + q) * 64 + l];
          acc[p][q] = __builtin_amdgcn_mfma_f32_16x16x32_f16(a, bb, acc[p][q], 0, 0, 0);
        } }
    { const f16x8 a = LDA(7); MF8(a, st); }

    // epilogue: LSTM cell
    f16* hw = hbuf[cp ^ 1];
#pragma unroll
    for (int p = 0; p < 2; ++p) {
      const int jh = 16 * (w + 8 * p) + c16;
#pragma unroll
      for (int r = 0; r < 4; ++r) {
        const float iv = acc[p][0][r], fv = acc[p][1][r], gv = acc[p][2][r], ov = acc[p][3][r];
        const float cn = sigf(fv) * cst[p][r] + sigf(iv) * tanh_(gv);
        cst[p][r] = cn;
        const float hn = sigf(ov) * tanh_(cn);
        const int bl = 4 * g + r;
        hw[bl * 264 + jh] = (f16)hn;
        if (t == T_ - 1) {
          hh0[(blk * 16 + bl) * H_ + jh] = hn;
          cc0[(blk * 16 + bl) * H_ + jh] = cn;
        }
      }
    }
    xac = xan;
    __syncthreads();
  }
  // final outs row: h(T-1) lives in hbuf[0] (T even)
  {
    const f16x8 hv = *(const f16x8*)(hbuf[0] + obl * 264 + ou * 8);
    *(f16x8*)(outs + ((size_t)(blk * 16 + obl) * T_ + (T_ - 1)) * H_ + ou * 8) = hv;
  }
#undef LDA
#undef MF8
#undef STAGE
}

// ---------------- eproj = outs.v + c0 ----------------
__global__ __launch_bounds__(256) void k_eproj(const f16* __restrict__ outs,
    const float* __restrict__ vv, float* __restrict__ eproj) {
  const int l = threadIdx.x & 63, wv = threadIdx.x >> 6;
  const float v0 = vv[4 * l], v1 = vv[4 * l + 1], v2 = vv[4 * l + 2], v3 = vv[4 * l + 3];
  const float c0 = vv[512];
  const int base = blockIdx.x * 256;
  for (int it = 0; it < 64; ++it) {
    const int row = base + it * 4 + wv;
    const f16x4 o = *(const f16x4*)(outs + (size_t)row * H_ + l * 4);
    float s = (float)o[0] * v0 + (float)o[1] * v1 + (float)o[2] * v2 + (float)o[3] * v3;
#pragma unroll
    for (int off = 32; off > 0; off >>= 1) s += __shfl_down(s, off);
    if (l == 0) eproj[row] = s + c0;
  }
}

// ---------------- fused persistent decoder: 1 block per batch, 24 steps in-kernel -------------
__global__ __launch_bounds__(512) void k_dec(const f16* __restrict__ outs,
    const float* __restrict__ eproj, const float* __restrict__ hh0, const float* __restrict__ cc0,
    const float* __restrict__ vv, const float* __restrict__ Wa, const float* __restrict__ Wo,
    const float* __restrict__ bo, const float* __restrict__ Wihd, const f16* __restrict__ wdT,
    float* __restrict__ dout) {
  const int b = blockIdx.x, tid = threadIdx.x;
  const int lane = tid & 63, wv = tid >> 6;
  __shared__ float epr[2048];                      // 8 KB
  __shared__ float wlds[2048];                     // 8 KB
  __shared__ float xL[512];                        // [ctx(256) | h(256)]
  __shared__ float cL[256];
  __shared__ float gL[1024];                       // 4 KB
  __shared__ float2 tmp[4][128];                   // 4 KB
  __shared__ float bdpL[1024], col0L[1024];        // 8 KB
  __shared__ float WaL[256], WoL[256];
  __shared__ float redD[8], redP[4], redS[4];
  __shared__ float sS, sInp, sDen, sBo;

  for (int i = tid; i < 2048; i += 512) epr[i] = eproj[(size_t)b * T_ + i];
  for (int i = tid; i < 1024; i += 512) { bdpL[i] = vv[576 + i]; col0L[i] = Wihd[i * 257]; }
  if (tid < 256) { WaL[tid] = Wa[tid]; WoL[tid] = Wo[tid]; }
  if (tid == 0) sBo = bo[0];
  // init h, c, token, s0
  float tokp = 0.f, s0p = 0.f;
  if (tid < 256) {
    const float hv = hh0[b * 256 + tid];
    xL[256 + tid] = hv;
    cL[tid] = cc0[b * 256 + tid];
    tokp = (float)outs[((size_t)b * T_ + (T_ - 1)) * 256 + tid] * vv[256 + tid];
    s0p = hv * Wa[tid];
  }
#pragma unroll
  for (int off = 32; off > 0; off >>= 1) { tokp += __shfl_down(tokp, off); s0p += __shfl_down(s0p, off); }
  if (lane == 0 && wv < 4) { redP[wv] = tokp; redS[wv] = s0p; }
  __syncthreads();
  if (tid == 0) {
    sInp = redP[0] + redP[1] + redP[2] + redP[3] + vv[513];
    sS = redS[0] + redS[1] + redS[2] + redS[3];
  }
  __syncthreads();

  const int q = tid >> 7, kp = tid & 127;
  for (int d = 0; d < TRG_; ++d) {
    // --- 1: attention weights (tanh bounds energies -> exp safe) + den partials ---
    const float s = sS;
    float den = 0.f;
#pragma unroll
    for (int i = 0; i < 4; ++i) {
      const int t = tid * 4 + i;
      const float w_ = __expf(tanh_(s + epr[t]));
      wlds[t] = w_;
      den += w_;
    }
#pragma unroll
    for (int off = 32; off > 0; off >>= 1) den += __shfl_down(den, off);
    if (lane == 0) redD[wv] = den;
    __syncthreads();
    if (tid == 0) {
      float ds = 0.f;
#pragma unroll
      for (int i2 = 0; i2 < 8; ++i2) ds += redD[i2];
      sDen = 1.0f / ds;
    }
    // --- 2: ctx accumulation (4-way t-split, f16x2 coalesced outs reads) ---
    {
      float cx = 0.f, cy = 0.f;
      const f16* op = outs + ((size_t)b * T_ + q * 512) * 256 + 2 * kp;
      const float* wp = wlds + q * 512;
#pragma unroll 4
      for (int t2 = 0; t2 < 512; ++t2) {
        const f16x2 ov = *(const f16x2*)op;
        const float wt = wp[t2];
        cx += wt * (float)ov[0];
        cy += wt * (float)ov[1];
        op += 256;
      }
      tmp[q][kp] = make_float2(cx, cy);
    }
    __syncthreads();
    if (tid < 128) {
      const float2 a0 = tmp[0][tid], a1 = tmp[1][tid], a2 = tmp[2][tid], a3 = tmp[3][tid];
      const float r = sDen;
      xL[2 * tid]     = (a0.x + a1.x + a2.x + a3.x) * r;
      xL[2 * tid + 1] = (a0.y + a1.y + a2.y + a3.y) * r;
    }
    __syncthreads();
    // --- 3: gates via k-major wdT (LDS broadcast x_k, coalesced f16x2 weight reads) ---
    {
      const int j0 = 2 * tid;
      float g0 = bdpL[j0] + col0L[j0] * sInp;
      float g1 = bdpL[j0 + 1] + col0L[j0 + 1] * sInp;
      const f16x2* wp2 = (const f16x2*)wdT + tid;
#pragma unroll 8
      for (int k = 0; k < 512; ++k) {
        const float xk = xL[k];
        const f16x2 wv2 = wp2[k * 512];
        g0 += xk * (float)wv2[0];
        g1 += xk * (float)wv2[1];
      }
      gL[j0] = g0; gL[j0 + 1] = g1;
    }
    __syncthreads();
    // --- 4: cell update + pred/snext reductions ---
    float pp = 0.f, ps = 0.f;
    if (tid < 256) {
      const float iv = gL[tid], fv = gL[256 + tid], gg = gL[512 + tid], ov = gL[768 + tid];
      const float cn = sigf(fv) * cL[tid] + sigf(iv) * tanh_(gg);
      cL[tid] = cn;
      const float hn = sigf(ov) * tanh_(cn);
      xL[256 + tid] = hn;
      pp = hn * WoL[tid];
      ps = hn * WaL[tid];
    }
#pragma unroll
    for (int off = 32; off > 0; off >>= 1) { pp += __shfl_down(pp, off); ps += __shfl_down(ps, off); }
    if (lane == 0 && wv < 4) { redP[wv] = pp; redS[wv] = ps; }
    __syncthreads();
    if (tid == 0) {
      const float pred = redP[0] + redP[1] + redP[2] + redP[3] + sBo;
      dout[b * TRG_ + d] = pred;
      sInp = pred;
      sS = redS[0] + redS[1] + redS[2] + redS[3];
    }
    __syncthreads();
  }
}

// ---------------- launch ----------------
extern "C" void kernel_launch(void* const* d_in, const int* in_sizes, int n_in,
                              void* d_out, int out_size, void* d_ws, size_t ws_size,
                              hipStream_t stream) {
  (void)in_sizes; (void)n_in; (void)out_size;
  float* dout = (float*)d_out;
  if (ws_size < WS_NEED) {
    k_wsfail<<<1, 1, 0, stream>>>(dout, (float)(ws_size >> 20));
    return;
  }
  const float* src1 = (const float*)d_in[0];
  const float* src2 = (const float*)d_in[1];
  const float* Wc   = (const float*)d_in[2];
  const float* bc   = (const float*)d_in[3];
  const float* Wihe = (const float*)d_in[4];
  const float* Whhe = (const float*)d_in[5];
  const float* bihe = (const float*)d_in[6];
  const float* bhhe = (const float*)d_in[7];
  const float* Wfc  = (const float*)d_in[8];
  const float* bfc  = (const float*)d_in[9];
  const float* Wf2  = (const float*)d_in[10];
  const float* bf2  = (const float*)d_in[11];
  const float* Wa   = (const float*)d_in[12];
  const float* Wihd = (const float*)d_in[13];
  const float* Whhd = (const float*)d_in[14];
  const float* bihd = (const float*)d_in[15];
  const float* bhhd = (const float*)d_in[16];
  const float* Wo   = (const float*)d_in[17];
  const float* bo   = (const float*)d_in[18];

  char* ws = (char*)d_ws;
  f16*   xf    = (f16*)(ws + XF_OFF);
  f16*   outs  = (f16*)(ws + OUTS_OFF);
  float* eproj = (float*)(ws + EPROJ_OFF);
  float* hh    = (float*)(ws + HH_OFF);
  float* cc    = (float*)(ws + CC_OFF);
  float* wxd   = (float*)(ws + WXD_OFF);
  float* vv    = (float*)(ws + VV_OFF);
  f16*   wall  = (f16*)(ws + WALL_OFF);
  f16*   w67   = (f16*)(ws + W67_OFF);
  f16*   xb    = (f16*)(ws + XB_OFF);
  f16*   wdT   = (f16*)(ws + WDT_OFF);

  k_setup<<<184, 256, 0, stream>>>(Wfc, Wa, Wf2, bf2, bfc, bihd, bhhd, Wihd,
                                   Whhe, Wihe, bihe, bhhe, vv, wxd, wall, w67, xb);
  k_wdt<<<512, 256, 0, stream>>>(wxd, Whhd, wdT);
  k_xf<<<B_ * 16, 128, 0, stream>>>(src1, src2, Wc, bc, xf);
  k_enc<<<NBLK, 512, 0, stream>>>(Whhe, wall, w67, xb, xf, outs, hh, cc);
  k_eproj<<<1024, 256, 0, stream>>>(outs, vv, eproj);
  k_dec<<<B_, 512, 0, stream>>>(outs, eproj, hh, cc, vv, Wa, Wo, bo, Wihd, wdT, dout);
}

// Round 14
// 9955.208 us; speedup vs baseline: 1.5920x; 1.1049x over previous
//
#include <hip/hip_runtime.h>
#include <hip/hip_fp16.h>

typedef __attribute__((ext_vector_type(4))) float f32x4;
typedef _Float16 f16;
typedef __attribute__((ext_vector_type(2))) _Float16 f16x2;
typedef __attribute__((ext_vector_type(4))) _Float16 f16x4;
typedef __attribute__((ext_vector_type(8))) _Float16 f16x8;

#define DEV static __device__ __forceinline__

constexpr int B_ = 128, T_ = 2048, H_ = 256, TRG_ = 24;
constexpr int NBLK = 8;   // encoder blocks, 16 batches each

// ---------------- workspace layout (~150 MiB) ----------------
constexpr size_t XF_OFF   = 0;                                   // x A-fragments [t][blk][bb][32] f16
constexpr size_t XF_BYTES = (size_t)T_ * NBLK * 16 * 32 * 2;     // 16 MiB
constexpr size_t OUTS_OFF = XF_OFF + XF_BYTES;
constexpr size_t OUTS_BYTES = (size_t)B_ * T_ * H_ * 2;          // 128 MiB f16
constexpr size_t EPROJ_OFF = OUTS_OFF + OUTS_BYTES;
constexpr size_t EPROJ_BYTES = (size_t)B_ * T_ * 4;              // (unused; kept for layout stability)
constexpr size_t HH_OFF = EPROJ_OFF + EPROJ_BYTES;               // enc final h (f32)
constexpr size_t HH_BYTES = 2ull * B_ * H_ * 4;
constexpr size_t CC_OFF = HH_OFF + HH_BYTES;                     // enc final c (f32)
constexpr size_t CC_BYTES = (size_t)B_ * H_ * 4;
constexpr size_t WXD_OFF = CC_OFF + CC_BYTES;                    // Wih_d[:,1:] @ Wfc (1024x256) f32
constexpr size_t WXD_BYTES = 1024ull * 256 * 4;
constexpr size_t VV_OFF = WXD_OFF + WXD_BYTES;
constexpr size_t VV_BYTES = 8192;
constexpr size_t WALL_OFF = VV_OFF + VV_BYTES;                   // enc weights ks0-3 image (f16 frags)
constexpr size_t WALL_BYTES = 16384ull * 16;                     // 256 KiB
constexpr size_t W67_OFF = WALL_OFF + WALL_BYTES;                // streamed enc weights ks6,7 (x2 copies)
constexpr size_t W67_BYTES = 2ull * 8192 * 16;                   // 256 KiB
constexpr size_t XB_OFF = W67_OFF + W67_BYTES;                   // streamed x weights (x2 copies)
constexpr size_t XB_BYTES = 2ull * 4096 * 16;                    // 128 KiB
constexpr size_t WDT_OFF = XB_OFF + XB_BYTES;                    // decoder weights T: [k512][j1024] f16
constexpr size_t WDT_BYTES = 512ull * 1024 * 2;                  // 1 MiB
constexpr size_t WS_NEED = WDT_OFF + WDT_BYTES + 1024;

// ---------------- helpers ----------------
DEV float sigf(float x)  { return 1.0f / (1.0f + __expf(-x)); }
DEV float tanh_(float x) { return 1.0f - 2.0f / (__expf(2.0f * x) + 1.0f); }

__global__ void k_wsfail(float* __restrict__ dout, float mb) { dout[0] = 1e6f + mb; }

// ---------------- merged setup: vv (blk<8), wxd (blk<72), enc weight images (else) -------------
__global__ void k_setup(const float* __restrict__ Wfc, const float* __restrict__ Wa,
                        const float* __restrict__ Wf2, const float* __restrict__ bf2_,
                        const float* __restrict__ bfc, const float* __restrict__ bihd,
                        const float* __restrict__ bhhd, const float* __restrict__ Wihd,
                        const float* __restrict__ Whh, const float* __restrict__ Wih,
                        const float* __restrict__ bih, const float* __restrict__ bhh,
                        float* __restrict__ vv, float* __restrict__ wxd,
                        f16* __restrict__ wall, f16* __restrict__ w67, f16* __restrict__ xb) {
  const int bid = blockIdx.x, tid = threadIdx.x;
  if (bid < 8) {
    const int blk = bid;
    if (blk == 0) {
      float a = 0; for (int h = 0; h < 256; ++h) a += Wfc[h * 256 + tid] * Wa[256 + h];
      vv[tid] = a;
    } else if (blk == 1) {
      float a = 0; for (int h = 0; h < 256; ++h) a += Wfc[h * 256 + tid] * Wf2[h];
      vv[256 + tid] = a;
    } else if (blk == 2) {
      if (tid == 0) { float a = 0; for (int h = 0; h < 256; ++h) a += bfc[h] * Wa[256 + h]; vv[512] = a; }
      if (tid == 1) { float a = bf2_[0]; for (int h = 0; h < 256; ++h) a += bfc[h] * Wf2[h]; vv[513] = a; }
    } else if (blk < 7) {
      int j = (blk - 3) * 256 + tid;
      float a = bihd[j] + bhhd[j];
      for (int h = 0; h < 256; ++h) a += Wihd[j * 257 + 1 + h] * bfc[h];
      vv[576 + j] = a;
    }
  } else if (bid < 72) {
    const int wb = bid - 8;
    __shared__ float sR[16][256];
    for (int i = tid; i < 16 * 256; i += 256) {
      int r = i >> 8, h = i & 255;
      sR[r][h] = Wihd[(wb * 16 + r) * 257 + 1 + h];
    }
    __syncthreads();
    const int k = tid;
    float a[16];
#pragma unroll
    for (int r = 0; r < 16; ++r) a[r] = 0.f;
    for (int h = 0; h < 256; ++h) {
      float wv = Wfc[h * 256 + k];
#pragma unroll
      for (int r = 0; r < 16; ++r) a[r] += sR[r][h] * wv;
    }
#pragma unroll
    for (int r = 0; r < 16; ++r) wxd[(wb * 16 + r) * 256 + k] = a[r];
  } else {
    int i = (bid - 72) * 256 + tid;
    if (i < 16384) {                 // wall ks0..3
      int l = i & 63, f = (i >> 6) & 63, ks = i >> 12;
      int q = f & 3, p = (f >> 2) & 1, w = f >> 3;
      int g = l >> 4, c16 = l & 15;
      int row = 256 * q + 16 * (w + 8 * p) + c16;
      f16x8 v;
#pragma unroll
      for (int jj = 0; jj < 8; ++jj) v[jj] = (f16)Whh[row * 256 + ks * 32 + 8 * g + jj];
      ((f16x8*)wall)[i] = v;
    } else if (i < 24576) {          // w67 ks6,7  (2 copies)
      int j = i - 16384;
      int l = j & 63, f = (j >> 6) & 63, ks = 6 + (j >> 12);
      int q = f & 3, p = (f >> 2) & 1, w = f >> 3;
      int g = l >> 4, c16 = l & 15;
      int row = 256 * q + 16 * (w + 8 * p) + c16;
      f16x8 v;
#pragma unroll
      for (int jj = 0; jj < 8; ++jj) v[jj] = (f16)Whh[row * 256 + ks * 32 + 8 * g + jj];
      ((f16x8*)w67)[j] = v;
      ((f16x8*)w67)[j + 8192] = v;
    } else if (i < 28672) {          // xb (2 copies)
      int j = i - 24576;
      int l = j & 63, f = (j >> 6) & 63;
      int q = f & 3, p = (f >> 2) & 1, w = f >> 3;
      int g = l >> 4, c16 = l & 15;
      int row = 256 * q + 16 * (w + 8 * p) + c16;
      f16x8 v;
#pragma unroll
      for (int jj = 0; jj < 8; ++jj) {
        int k = 8 * g + jj;
        float val = (k < 16) ? Wih[row * 16 + k] : (k == 16 ? (bih[row] + bhh[row]) : 0.f);
        v[jj] = (f16)val;
      }
      ((f16x8*)xb)[j] = v;
      ((f16x8*)xb)[j + 4096] = v;
    }
  }
}

// ---------------- decoder weight transpose: wdT[k][j] (k<256: wxd, else Whhd), f16 ------------
__global__ void k_wdt(const float* __restrict__ wxd, const float* __restrict__ Whhd,
                      f16* __restrict__ wdT) {
  const int k = blockIdx.x, tid = threadIdx.x;
#pragma unroll
  for (int j4 = 0; j4 < 4; ++j4) {
    const int j = j4 * 256 + tid;
    const float val = (k < 256) ? wxd[j * 256 + k] : Whhd[j * 256 + (k - 256)];
    wdT[(size_t)k * 1024 + j] = (f16)val;
  }
}

// ---------------- x A-fragment prepass (coalesced) ----------------
__global__ __launch_bounds__(128) void k_xf(const float* __restrict__ src1,
    const float* __restrict__ src2, const float* __restrict__ Wc, const float* __restrict__ bc,
    f16* __restrict__ xf) {
  const int b = blockIdx.x >> 4, tc = blockIdx.x & 15;
  const int t = tc * 128 + threadIdx.x;
  f16x8 v0, v1, v2, v3;
#pragma unroll
  for (int f = 0; f < 8; ++f)  v0[f] = (f16)src1[((size_t)b * T_ + t) * 15 + f];
#pragma unroll
  for (int f = 0; f < 7; ++f)  v1[f] = (f16)src1[((size_t)b * T_ + t) * 15 + 8 + f];
  float s = bc[0];
#pragma unroll
  for (int u = 0; u < 8; ++u) s += src2[((size_t)b * T_ + t) * 8 + u] * Wc[u];
  v1[7] = (f16)s;
  v2 = (f16x8){(f16)1.f, (f16)0.f, (f16)0.f, (f16)0.f, (f16)0.f, (f16)0.f, (f16)0.f, (f16)0.f};
  v3 = (f16x8){(f16)0.f, (f16)0.f, (f16)0.f, (f16)0.f, (f16)0.f, (f16)0.f, (f16)0.f, (f16)0.f};
  f16* o = xf + (((size_t)t * 8 + (b >> 4)) * 16 + (b & 15)) * 32;
  *(f16x8*)(o) = v0; *(f16x8*)(o + 8) = v1; *(f16x8*)(o + 16) = v2; *(f16x8*)(o + 24) = v3;
}

// ---------------- encoder: R10 structure (best measured, FROZEN) ----------
__global__ __launch_bounds__(512, 2) void k_enc(const float* __restrict__ Whh,
    const f16* __restrict__ wall, const f16* __restrict__ w67, const f16* __restrict__ xb,
    const f16* __restrict__ xf, f16* __restrict__ outs,
    float* __restrict__ hh0, float* __restrict__ cc0) {
  const int blk = blockIdx.x, tid = threadIdx.x;
  const int w = tid >> 6, l = tid & 63, g = l >> 4, c16 = l & 15;
  __shared__ f16x8 Wl[8192];                      // ks4,5: [((ksl*8+w)*2+p)*4+q][lane] = 128 KiB
  __shared__ __align__(16) f16 hbuf[2][16 * 264]; // ping-pong h[b][jh], stride 264

  // LDS-resident weights ks4,5 (setup-only f32 read)
#pragma unroll
  for (int ksl = 0; ksl < 2; ++ksl)
#pragma unroll
    for (int p = 0; p < 2; ++p)
#pragma unroll
      for (int q = 0; q < 4; ++q) {
        const int row = 256 * q + 16 * (w + 8 * p) + c16;
        const float* s = Whh + row * 256 + (4 + ksl) * 32 + 8 * g;
        f16x8 v;
#pragma unroll
        for (int jj = 0; jj < 8; ++jj) v[jj] = (f16)s[jj];
        Wl[((((ksl * 8 + w) * 2 + p) * 4 + q)) * 64 + l] = v;
      }
  // ks0..3 weights from f16 fragment image
  const f16x8* wallv = (const f16x8*)wall;
  f16x8 wf[4][2][4];
#pragma unroll
  for (int ks = 0; ks < 4; ++ks)
#pragma unroll
    for (int p = 0; p < 2; ++p)
#pragma unroll
      for (int q = 0; q < 4; ++q)
        wf[ks][p][q] = wallv[(size_t)(ks * 64 + w * 8 + p * 4 + q) * 64 + l];
  for (int i = tid; i < 16 * 264; i += 512) hbuf[0][i] = (f16)0.f;
  __syncthreads();

  f32x4 cst[2];
  cst[0] = (f32x4){0.f, 0.f, 0.f, 0.f};
  cst[1] = (f32x4){0.f, 0.f, 0.f, 0.f};

  const f16x8* w67v = (const f16x8*)w67;
  const f16x8* xbv = (const f16x8*)xb;
  const int fb = w * 8;
  const int obl = tid >> 5, ou = tid & 31;        // outs-writer mapping

#define LDA(ks) (*(const f16x8*)(hb + c16 * 264 + (ks) * 32 + 8 * g))
#define MF8(A, BB) \
  { _Pragma("unroll") for (int p = 0; p < 2; ++p) \
    _Pragma("unroll") for (int q = 0; q < 4; ++q) \
      acc[p][q] = __builtin_amdgcn_mfma_f32_16x16x32_f16((A), BB[p][q], acc[p][q], 0, 0, 0); }
#define STAGE(SRC) \
  { _Pragma("unroll") for (int p = 0; p < 2; ++p) \
    _Pragma("unroll") for (int q = 0; q < 4; ++q) \
      st[p][q] = (SRC)[(size_t)(fb + p * 4 + q) * 64 + l]; }

  f16x8 xac = *(const f16x8*)(xf + ((size_t)blk * 16 + c16) * 32 + 8 * g);   // t=0

  for (int t = 0; t < T_; ++t) {
    const int cp = t & 1;
    const f16* hb = hbuf[cp];
    const f16x8* sx = xbv + (size_t)cp * 4096;
    const f16x8* s6 = w67v + (size_t)cp * 8192;
    const f16x8* s7 = s6 + 4096;

    f16x8 st[2][4];
    STAGE(sx);
    const int tn = (t + 1 < T_) ? (t + 1) : t;
    const f16x8 xan = *(const f16x8*)(xf + (((size_t)tn * 8 + blk) * 16 + c16) * 32 + 8 * g);

    // coalesced outs write of h(t-1), drains under MFMAs
    if (t > 0) {
      const f16x8 hv = *(const f16x8*)(hb + obl * 264 + ou * 8);
      *(f16x8*)(outs + ((size_t)(blk * 16 + obl) * T_ + (t - 1)) * H_ + ou * 8) = hv;
    }

    f32x4 acc[2][4];
#pragma unroll
    for (int p = 0; p < 2; ++p)
#pragma unroll
      for (int q = 0; q < 4; ++q) acc[p][q] = (f32x4){0.f, 0.f, 0.f, 0.f};

    { const f16x8 a = LDA(0); MF8(a, wf[0]); }
    { const f16x8 a = LDA(1); MF8(a, wf[1]); }
    { const f16x8 a = LDA(2); MF8(a, wf[2]); }
    MF8(xac, st);
    STAGE(s6);
    { const f16x8 a = LDA(3); MF8(a, wf[3]); }
    { const f16x8 a = LDA(4);
#pragma unroll
      for (int p = 0; p < 2; ++p)
#pragma unroll
        for (int q = 0; q < 4; ++q) {
          const f16x8 bb = Wl[(((0 * 8 + w) * 2 + p) * 4 + q) * 64 + l];
          acc[p][q] = __builtin_amdgcn_mfma_f32_16x16x32_f16(a, bb, acc[p][q], 0, 0, 0);
        } }
    { const f16x8 a = LDA(6); MF8(a, st); }
    STAGE(s7);
    { const f16x8 a = LDA(5);
#pragma unroll
      for (int p = 0; p < 2; ++p)
#pragma unroll
        for (int q = 0; q < 4; ++q) {
          const f16x8 bb = Wl[(((1 * 8 + w) * 2 + p) * 4 + q) * 64 + l];
          acc[p][q] = __builtin_amdgcn_mfma_f32_16x16x32_f16(a, bb, acc[p][q], 0, 0, 0);
        } }
    { const f16x8 a = LDA(7); MF8(a, st); }

    // epilogue: LSTM cell
    f16* hw = hbuf[cp ^ 1];
#pragma unroll
    for (int p = 0; p < 2; ++p) {
      const int jh = 16 * (w + 8 * p) + c16;
#pragma unroll
      for (int r = 0; r < 4; ++r) {
        const float iv = acc[p][0][r], fv = acc[p][1][r], gv = acc[p][2][r], ov = acc[p][3][r];
        const float cn = sigf(fv) * cst[p][r] + sigf(iv) * tanh_(gv);
        cst[p][r] = cn;
        const float hn = sigf(ov) * tanh_(cn);
        const int bl = 4 * g + r;
        hw[bl * 264 + jh] = (f16)hn;
        if (t == T_ - 1) {
          hh0[(blk * 16 + bl) * H_ + jh] = hn;
          cc0[(blk * 16 + bl) * H_ + jh] = cn;
        }
      }
    }
    xac = xan;
    __syncthreads();
  }
  // final outs row: h(T-1) lives in hbuf[0] (T even)
  {
    const f16x8 hv = *(const f16x8*)(hbuf[0] + obl * 264 + ou * 8);
    *(f16x8*)(outs + ((size_t)(blk * 16 + obl) * T_ + (T_ - 1)) * H_ + ou * 8) = hv;
  }
#undef LDA
#undef MF8
#undef STAGE
}

// ---------------- fused persistent decoder: 1 block/batch, eproj computed in-kernel -----------
__global__ __launch_bounds__(512) void k_dec(const f16* __restrict__ outs,
    const float* __restrict__ hh0, const float* __restrict__ cc0,
    const float* __restrict__ vv, const float* __restrict__ Wa, const float* __restrict__ Wo,
    const float* __restrict__ bo, const float* __restrict__ Wihd, const f16* __restrict__ wdT,
    float* __restrict__ dout) {
  const int b = blockIdx.x, tid = threadIdx.x;
  const int lane = tid & 63, wv = tid >> 6;
  __shared__ __align__(16) float epr[2048];        // 8 KB (energies, computed in-kernel)
  __shared__ __align__(16) float wlds[2048];       // 8 KB
  __shared__ __align__(16) float xL[512];          // [ctx(256) | h(256)]
  __shared__ float cL[256];
  __shared__ float gL[1024];
  __shared__ float2 tmp[4][128];
  __shared__ float bdpL[1024], col0L[1024];
  __shared__ __align__(16) float vL[256];
  __shared__ float WaL[256], WoL[256];
  __shared__ float redD[8], redP[4], redS[4];
  __shared__ float sS, sInp, sDen, sBo;

  for (int i = tid; i < 1024; i += 512) { bdpL[i] = vv[576 + i]; col0L[i] = Wihd[i * 257]; }
  if (tid < 256) { vL[tid] = vv[tid]; WaL[tid] = Wa[tid]; WoL[tid] = Wo[tid]; }
  if (tid == 0) sBo = bo[0];
  // init h, c, token, s0
  float tokp = 0.f, s0p = 0.f;
  if (tid < 256) {
    const float hv = hh0[b * 256 + tid];
    xL[256 + tid] = hv;
    cL[tid] = cc0[b * 256 + tid];
    tokp = (float)outs[((size_t)b * T_ + (T_ - 1)) * 256 + tid] * vv[256 + tid];
    s0p = hv * Wa[tid];
  }
#pragma unroll
  for (int off = 32; off > 0; off >>= 1) { tokp += __shfl_down(tokp, off); s0p += __shfl_down(s0p, off); }
  if (lane == 0 && wv < 4) { redP[wv] = tokp; redS[wv] = s0p; }
  __syncthreads();
  if (tid == 0) {
    sInp = redP[0] + redP[1] + redP[2] + redP[3] + vv[513];
    sS = redS[0] + redS[1] + redS[2] + redS[3];
  }
  // ---- eproj into LDS: wave wv handles t = it*8 + wv ----
  {
    const float c0 = vv[512];
    const float4 v4 = *(const float4*)&vL[lane * 4];
    for (int it = 0; it < 256; ++it) {
      const int t = it * 8 + wv;
      const f16x4 o = *(const f16x4*)(outs + ((size_t)b * T_ + t) * 256 + lane * 4);
      float s = (float)o[0] * v4.x + (float)o[1] * v4.y + (float)o[2] * v4.z + (float)o[3] * v4.w;
#pragma unroll
      for (int off = 32; off > 0; off >>= 1) s += __shfl_down(s, off);
      if (lane == 0) epr[t] = s + c0;
    }
  }
  __syncthreads();

  const int q = tid >> 7, kp = tid & 127;
  const f16* opb = outs + ((size_t)b * T_ + q * 512) * 256 + 2 * kp;
  for (int d = 0; d < TRG_; ++d) {
    // --- 1: attention weights (tanh bounds energies -> exp safe) + den partials ---
    const float s = sS;
    float den = 0.f;
#pragma unroll
    for (int i = 0; i < 4; ++i) {
      const int t = tid * 4 + i;
      const float w_ = __expf(tanh_(s + epr[t]));
      wlds[t] = w_;
      den += w_;
    }
#pragma unroll
    for (int off = 32; off > 0; off >>= 1) den += __shfl_down(den, off);
    if (lane == 0) redD[wv] = den;
    __syncthreads();
    if (tid == 0) {
      float ds = 0.f;
#pragma unroll
      for (int i2 = 0; i2 < 8; ++i2) ds += redD[i2];
      sDen = 1.0f / ds;
    }
    // --- 2: ctx accumulation (4-way t-split, unroll-8 indexed, b128 LDS weight reads) ---
    {
      float cx = 0.f, cy = 0.f;
      for (int t8 = 0; t8 < 512; t8 += 8) {
        const float4 wa = *(const float4*)(wlds + q * 512 + t8);
        const float4 wb = *(const float4*)(wlds + q * 512 + t8 + 4);
        const f16* op8 = opb + (size_t)t8 * 256;
#pragma unroll
        for (int i = 0; i < 8; ++i) {
          const f16x2 ov = *(const f16x2*)(op8 + i * 256);
          const float wt = (i < 4) ? ((const float*)&wa)[i] : ((const float*)&wb)[i - 4];
          cx += wt * (float)ov[0];
          cy += wt * (float)ov[1];
        }
      }
      tmp[q][kp] = make_float2(cx, cy);
    }
    __syncthreads();
    if (tid < 128) {
      const float2 a0 = tmp[0][tid], a1 = tmp[1][tid], a2 = tmp[2][tid], a3 = tmp[3][tid];
      const float r = sDen;
      xL[2 * tid]     = (a0.x + a1.x + a2.x + a3.x) * r;
      xL[2 * tid + 1] = (a0.y + a1.y + a2.y + a3.y) * r;
    }
    __syncthreads();
    // --- 3: gates via k-major wdT (b128 LDS x reads, coalesced f16x2 weight reads) ---
    {
      const int j0 = 2 * tid;
      float g0 = bdpL[j0] + col0L[j0] * sInp;
      float g1 = bdpL[j0 + 1] + col0L[j0 + 1] * sInp;
      const f16x2* wp2 = (const f16x2*)wdT + tid;
      for (int k4 = 0; k4 < 512; k4 += 4) {
        const float4 xv = *(const float4*)(xL + k4);
        const f16x2 w0 = wp2[(k4 + 0) * 512];
        const f16x2 w1 = wp2[(k4 + 1) * 512];
        const f16x2 w2 = wp2[(k4 + 2) * 512];
        const f16x2 w3 = wp2[(k4 + 3) * 512];
        g0 += xv.x * (float)w0[0] + xv.y * (float)w1[0] + xv.z * (float)w2[0] + xv.w * (float)w3[0];
        g1 += xv.x * (float)w0[1] + xv.y * (float)w1[1] + xv.z * (float)w2[1] + xv.w * (float)w3[1];
      }
      gL[j0] = g0; gL[j0 + 1] = g1;
    }
    __syncthreads();
    // --- 4: cell update + pred/snext reductions ---
    float pp = 0.f, ps = 0.f;
    if (tid < 256) {
      const float iv = gL[tid], fv = gL[256 + tid], gg = gL[512 + tid], ov = gL[768 + tid];
      const float cn = sigf(fv) * cL[tid] + sigf(iv) * tanh_(gg);
      cL[tid] = cn;
      const float hn = sigf(ov) * tanh_(cn);
      xL[256 + tid] = hn;
      pp = hn * WoL[tid];
      ps = hn * WaL[tid];
    }
#pragma unroll
    for (int off = 32; off > 0; off >>= 1) { pp += __shfl_down(pp, off); ps += __shfl_down(ps, off); }
    if (lane == 0 && wv < 4) { redP[wv] = pp; redS[wv] = ps; }
    __syncthreads();
    if (tid == 0) {
      const float pred = redP[0] + redP[1] + redP[2] + redP[3] + sBo;
      dout[b * TRG_ + d] = pred;
      sInp = pred;
      sS = redS[0] + redS[1] + redS[2] + redS[3];
    }
    __syncthreads();
  }
}

// ---------------- launch ----------------
extern "C" void kernel_launch(void* const* d_in, const int* in_sizes, int n_in,
                              void* d_out, int out_size, void* d_ws, size_t ws_size,
                              hipStream_t stream) {
  (void)in_sizes; (void)n_in; (void)out_size;
  float* dout = (float*)d_out;
  if (ws_size < WS_NEED) {
    k_wsfail<<<1, 1, 0, stream>>>(dout, (float)(ws_size >> 20));
    return;
  }
  const float* src1 = (const float*)d_in[0];
  const float* src2 = (const float*)d_in[1];
  const float* Wc   = (const float*)d_in[2];
  const float* bc   = (const float*)d_in[3];
  const float* Wihe = (const float*)d_in[4];
  const float* Whhe = (const float*)d_in[5];
  const float* bihe = (const float*)d_in[6];
  const float* bhhe = (const float*)d_in[7];
  const float* Wfc  = (const float*)d_in[8];
  const float* bfc  = (const float*)d_in[9];
  const float* Wf2  = (const float*)d_in[10];
  const float* bf2  = (const float*)d_in[11];
  const float* Wa   = (const float*)d_in[12];
  const float* Wihd = (const float*)d_in[13];
  const float* Whhd = (const float*)d_in[14];
  const float* bihd = (const float*)d_in[15];
  const float* bhhd = (const float*)d_in[16];
  const float* Wo   = (const float*)d_in[17];
  const float* bo   = (const float*)d_in[18];

  char* ws = (char*)d_ws;
  f16*   xf    = (f16*)(ws + XF_OFF);
  f16*   outs  = (f16*)(ws + OUTS_OFF);
  float* hh    = (float*)(ws + HH_OFF);
  float* cc    = (float*)(ws + CC_OFF);
  float* wxd   = (float*)(ws + WXD_OFF);
  float* vv    = (float*)(ws + VV_OFF);
  f16*   wall  = (f16*)(ws + WALL_OFF);
  f16*   w67   = (f16*)(ws + W67_OFF);
  f16*   xb    = (f16*)(ws + XB_OFF);
  f16*   wdT   = (f16*)(ws + WDT_OFF);

  k_setup<<<184, 256, 0, stream>>>(Wfc, Wa, Wf2, bf2, bfc, bihd, bhhd, Wihd,
                                   Whhe, Wihe, bihe, bhhe, vv, wxd, wall, w67, xb);
  k_wdt<<<512, 256, 0, stream>>>(wxd, Whhd, wdT);
  k_xf<<<B_ * 16, 128, 0, stream>>>(src1, src2, Wc, bc, xf);
  k_enc<<<NBLK, 512, 0, stream>>>(Whhe, wall, w67, xb, xf, outs, hh, cc);
  k_dec<<<B_, 512, 0, stream>>>(outs, hh, cc, vv, Wa, Wo, bo, Wihd, wdT, dout);
}